// Round 2
// baseline (294.886 us; speedup 1.0000x reference)
//
#include <hip/hip_runtime.h>
#include <math.h>

#define NN 4096
#define EE 8192
#define HH 128
#define GG 8
#define ULD 4352          // big GEMM cols: 4096 (W2) + 128 (b2) + 128 (root)

typedef __attribute__((ext_vector_type(8))) _Float16 half8;
typedef __attribute__((ext_vector_type(4))) float floatx4;

__device__ __forceinline__ void ldst16(const _Float16* g, void* l) {
    __builtin_amdgcn_global_load_lds(
        (const __attribute__((address_space(1))) unsigned int*)g,
        (__attribute__((address_space(3))) unsigned int*)l, 16, 0, 0);
}

// ---------------------------------------------------------------------------
// fp16 MFMA GEMM: C[M,*] = A[M,128] @ BT[N,128]^T, C stored fp16.
// 128x128 tile/block, 4 waves (2x2 of 64x64), BK=32, K=128 (4 iters).
// Dead-channel pruning: blockIdx.x < 32 indexes a W2 k-slice; if kflag bit
// clear the slice is never read -> exit. Alive slices write COMPACTED cols.
// ---------------------------------------------------------------------------
__global__ __launch_bounds__(256) void mgemm16_k(
    const _Float16* __restrict__ A, const _Float16* __restrict__ B,
    _Float16* __restrict__ C, const int* __restrict__ kflag)
{
    const int kk = blockIdx.x;
    int cbase;
    if (kk < 32) {
        const unsigned f = *(const unsigned*)kflag;
        if (!((f >> kk) & 1u)) return;               // dead slice: no reader
        cbase = __popc(f & ((1u << kk) - 1u)) << 7;  // compacted col slot
    } else {
        cbase = kk << 7;                             // b2 / root fixed slots
    }

    __shared__ __align__(16) _Float16 As[128 * 32];  // [row][k]
    __shared__ __align__(16) _Float16 Bs[128 * 32];  // [col][k]
    const int tid = threadIdx.x;
    const int lane = tid & 63, wave = tid >> 6;
    const int m0 = blockIdx.y * 128, n0 = kk * 128;  // n0: weight-row base
    const int wr = (wave >> 1) * 64, wc = (wave & 1) * 64;
    const int fm = lane & 15, fq = lane >> 4;

    const int srow = tid >> 2, soff = (tid & 3) << 3;
    const _Float16* gA0 = A + (size_t)(m0 + srow) * 128 + soff;
    const _Float16* gA1 = gA0 + (size_t)64 * 128;
    const _Float16* gB0 = B + (size_t)(n0 + srow) * 128 + soff;
    const _Float16* gB1 = gB0 + (size_t)64 * 128;
    char* lA0 = (char*)As + tid * 16;  char* lA1 = (char*)As + (tid + 256) * 16;
    char* lB0 = (char*)Bs + tid * 16;  char* lB1 = (char*)Bs + (tid + 256) * 16;

    floatx4 acc[4][4] = {};
    for (int k0 = 0; k0 < 128; k0 += 32) {
        __syncthreads();
        ldst16(gA0 + k0, lA0); ldst16(gA1 + k0, lA1);
        ldst16(gB0 + k0, lB0); ldst16(gB1 + k0, lB1);
        __syncthreads();
        half8 af[4], bf[4];
#pragma unroll
        for (int i = 0; i < 4; ++i)
            af[i] = *(const half8*)&As[(wr + i * 16 + fm) * 32 + fq * 8];
#pragma unroll
        for (int j = 0; j < 4; ++j)
            bf[j] = *(const half8*)&Bs[(wc + j * 16 + fm) * 32 + fq * 8];
#pragma unroll
        for (int i = 0; i < 4; ++i)
#pragma unroll
            for (int j = 0; j < 4; ++j)
                acc[i][j] = __builtin_amdgcn_mfma_f32_16x16x32_f16(
                    af[i], bf[j], acc[i][j], 0, 0, 0);
    }
    // C/D layout: col = lane&15, row = (lane>>4)*4 + reg  [m89; dtype-indep]
    const int er = fq * 4, ec = fm;
#pragma unroll
    for (int i = 0; i < 4; ++i) {
        const int gr = m0 + wr + i * 16 + er;
#pragma unroll
        for (int j = 0; j < 4; ++j) {
            const int gc = cbase + wc + j * 16 + ec;
#pragma unroll
            for (int r = 0; r < 4; ++r)
                C[(size_t)(gr + r) * ULD + gc] = (_Float16)acc[i][j][r];
        }
    }
}

// ---------------------------------------------------------------------------
// FUSED GRU: computes gi = m @ Wih^T and gh = h @ Whh^T for a 64-row stripe
// and a 32-col group, then applies the gate combine in the epilogue.
// Col-group c owns output cols oc in [32c, 32c+32); B staging covers weight
// rows {oc, 128+oc, 256+oc} of BOTH matrices, so the 12 acc tiles per wave
// are lane-aligned -> combine is pure register math (no LDS exchange, no
// g1/g2 round-trip). m = relu(bigC_root + agg + cb) fused into A-staging.
// h ping-pong: reads xh_in/Ax_in, writes xh_out/Ax_out (cross-block race
// safety). Pooling fused on last step.
// grid (4, 64), 256 threads (4 waves, 16 rows/wave).
// ---------------------------------------------------------------------------
__global__ __launch_bounds__(256) void gru_gate_k(
    const _Float16* __restrict__ bigC, const float* __restrict__ agg,
    const float* __restrict__ cb, const _Float16* __restrict__ Ax_in,
    const float* __restrict__ xh_in,
    const _Float16* __restrict__ Bih, const _Float16* __restrict__ Bhh,
    const float* __restrict__ bih, const float* __restrict__ bhh,
    float* __restrict__ xh_out, _Float16* __restrict__ Ax_out,
    const int* __restrict__ batch, float* __restrict__ pooled)
{
    __shared__ __align__(16) _Float16 As_m[64 * 40];
    __shared__ __align__(16) _Float16 As_h[64 * 40];
    __shared__ __align__(16) _Float16 Bsi[96 * 40];
    __shared__ __align__(16) _Float16 Bsh[96 * 40];
    const int tid = threadIdx.x;
    const int lane = tid & 63, wave = tid >> 6;
    const int c0 = blockIdx.x * 32;      // output col group [c0, c0+32)
    const int m0 = blockIdx.y * 64;      // row stripe
    const int fm = lane & 15, fq = lane >> 4;

    floatx4 accI[3][2] = {};
    floatx4 accH[3][2] = {};

    for (int k0 = 0; k0 < 128; k0 += 32) {
        __syncthreads();
#pragma unroll
        for (int it = 0; it < 5; ++it) {
            const int idx = tid + it * 256;           // 1280 items
            const int row = idx >> 2, seg = (idx & 3) << 3;
            if (row < 64) {                           // A_m: m = relu(root+agg+cb)
                const int mr = m0 + row;
                const half8 cv = *(const half8*)&bigC[(size_t)mr * ULD + 4224 + k0 + seg];
                const float4 a0 = *(const float4*)&agg[(size_t)mr * 128 + k0 + seg];
                const float4 a1 = *(const float4*)&agg[(size_t)mr * 128 + k0 + seg + 4];
                const float4 b0 = *(const float4*)&cb[k0 + seg];
                const float4 b1 = *(const float4*)&cb[k0 + seg + 4];
                _Float16 v8[8];
                float v;
                v = (float)cv[0] + a0.x + b0.x; v8[0] = (_Float16)(v > 0.f ? v : 0.f);
                v = (float)cv[1] + a0.y + b0.y; v8[1] = (_Float16)(v > 0.f ? v : 0.f);
                v = (float)cv[2] + a0.z + b0.z; v8[2] = (_Float16)(v > 0.f ? v : 0.f);
                v = (float)cv[3] + a0.w + b0.w; v8[3] = (_Float16)(v > 0.f ? v : 0.f);
                v = (float)cv[4] + a1.x + b1.x; v8[4] = (_Float16)(v > 0.f ? v : 0.f);
                v = (float)cv[5] + a1.y + b1.y; v8[5] = (_Float16)(v > 0.f ? v : 0.f);
                v = (float)cv[6] + a1.z + b1.z; v8[6] = (_Float16)(v > 0.f ? v : 0.f);
                v = (float)cv[7] + a1.w + b1.w; v8[7] = (_Float16)(v > 0.f ? v : 0.f);
                *(half8*)&As_m[row * 40 + seg] = *(half8*)v8;
            } else if (row < 128) {                   // A_h from Ax_in
                const int r = row - 64;
                *(half8*)&As_h[r * 40 + seg] =
                    *(const half8*)&Ax_in[(size_t)(m0 + r) * 128 + k0 + seg];
            } else if (row < 224) {                   // Wih rows {p*128+c0+rr}
                const int r = row - 128, p = r >> 5, rr = r & 31;
                *(half8*)&Bsi[r * 40 + seg] =
                    *(const half8*)&Bih[(size_t)(p * 128 + c0 + rr) * 128 + k0 + seg];
            } else {                                  // Whh rows
                const int r = row - 224, p = r >> 5, rr = r & 31;
                *(half8*)&Bsh[r * 40 + seg] =
                    *(const half8*)&Bhh[(size_t)(p * 128 + c0 + rr) * 128 + k0 + seg];
            }
        }
        __syncthreads();
        const half8 am = *(const half8*)&As_m[(wave * 16 + fm) * 40 + fq * 8];
        const half8 ah = *(const half8*)&As_h[(wave * 16 + fm) * 40 + fq * 8];
#pragma unroll
        for (int p = 0; p < 3; ++p)
#pragma unroll
            for (int jj = 0; jj < 2; ++jj) {
                const half8 bi = *(const half8*)&Bsi[(p * 32 + jj * 16 + fm) * 40 + fq * 8];
                const half8 bh = *(const half8*)&Bsh[(p * 32 + jj * 16 + fm) * 40 + fq * 8];
                accI[p][jj] = __builtin_amdgcn_mfma_f32_16x16x32_f16(
                    am, bi, accI[p][jj], 0, 0, 0);
                accH[p][jj] = __builtin_amdgcn_mfma_f32_16x16x32_f16(
                    ah, bh, accH[p][jj], 0, 0, 0);
            }
    }
    // epilogue: lane-aligned gate combine. row = m0+wave*16+fq*4+rr,
    // oc = c0+jj*16+fm; acc tiles for r/z/n parts share (jj,fm,fq,rr).
    const int rbase = m0 + wave * 16 + fq * 4;
#pragma unroll
    for (int jj = 0; jj < 2; ++jj) {
        const int oc = c0 + jj * 16 + fm;
        const float bir = bih[oc],        bhr = bhh[oc];
        const float biz = bih[128 + oc],  bhz = bhh[128 + oc];
        const float bin_ = bih[256 + oc], bhn = bhh[256 + oc];
#pragma unroll
        for (int rr = 0; rr < 4; ++rr) {
            const int row = rbase + rr;
            const float ir = accI[0][jj][rr] + bir, hr = accH[0][jj][rr] + bhr;
            const float iz = accI[1][jj][rr] + biz, hz = accH[1][jj][rr] + bhz;
            const float in_ = accI[2][jj][rr] + bin_, hn = accH[2][jj][rr] + bhn;
            const float rg = 1.f / (1.f + expf(-(ir + hr)));
            const float zg = 1.f / (1.f + expf(-(iz + hz)));
            const float nv = tanhf(in_ + rg * hn);
            const float hv = (1.f - zg) * nv + zg * xh_in[(size_t)row * 128 + oc];
            xh_out[(size_t)row * 128 + oc] = hv;
            Ax_out[(size_t)row * 128 + oc] = (_Float16)hv;
            if (pooled) atomicAdd(&pooled[batch[row] * 128 + oc], hv);
        }
    }
}

// ---------------------------------------------------------------------------
// FUSED setup: b<192 GRU weight cast; b<224 degree hists; b<240 graph count;
// b>=240 lin0 GEMM (xh = relu(x @ w + b), also writes Ax fp16).
// ---------------------------------------------------------------------------
__global__ __launch_bounds__(256) void setup_lin0_k(
    const float* __restrict__ wih, const float* __restrict__ whh,
    _Float16* __restrict__ Bih, _Float16* __restrict__ Bhh,
    const int* __restrict__ ei, const int* __restrict__ batch,
    float* __restrict__ deg, int* __restrict__ odeg, float* __restrict__ cnt,
    const float* __restrict__ x, const float* __restrict__ l0w,
    const float* __restrict__ l0b, float* __restrict__ xh,
    _Float16* __restrict__ Ax)
{
    __shared__ float loc8[GG];
    __shared__ float As[16][64];
    __shared__ float Bs[16][64];
    const int b = blockIdx.x, t = threadIdx.x;
    if (b < 192) {
        const int idx = b * 256 + t;           // 384*128
        Bih[idx] = (_Float16)wih[idx];
        Bhh[idx] = (_Float16)whh[idx];
    } else if (b < 224) {
        const int e = (b - 192) * 256 + t;     // 8192
        atomicAdd(&deg[ei[EE + e]], 1.0f);
        atomicAdd(&odeg[ei[e]], 1);
    } else if (b < 240) {
        const int n = (b - 224) * 256 + t;     // 4096
        if (t < GG) loc8[t] = 0.f;
        __syncthreads();
        atomicAdd(&loc8[batch[n]], 1.0f);
        __syncthreads();
        if (t < GG) atomicAdd(&cnt[t], loc8[t]);
    } else {
        // lin0: 128 blocks, 64x64 tile
        const int bb = b - 240;
        const int j0 = (bb & 1) * 64;
        const int m0 = (bb >> 1) * 64;
        const int tx = t & 15, ty = t >> 4;
        const int arow = t >> 2, acol = (t & 3) << 2;
        const int bk = t >> 4, bj = (t & 15) << 2;
        float c[4][4] = {};
        for (int k0 = 0; k0 < 64; k0 += 16) {
            __syncthreads();
            float4 av = *(const float4*)&x[(size_t)(m0 + arow) * 64 + k0 + acol];
            As[acol + 0][arow] = av.x;
            As[acol + 1][arow] = av.y;
            As[acol + 2][arow] = av.z;
            As[acol + 3][arow] = av.w;
            *(float4*)&Bs[bk][bj] = *(const float4*)&l0w[(size_t)(k0 + bk) * 128 + j0 + bj];
            __syncthreads();
#pragma unroll
            for (int kk = 0; kk < 16; ++kk) {
                const float4 a = *(const float4*)&As[kk][ty << 2];
                const float4 bv = *(const float4*)&Bs[kk][tx << 2];
                c[0][0] += a.x * bv.x; c[0][1] += a.x * bv.y; c[0][2] += a.x * bv.z; c[0][3] += a.x * bv.w;
                c[1][0] += a.y * bv.x; c[1][1] += a.y * bv.y; c[1][2] += a.y * bv.z; c[1][3] += a.y * bv.w;
                c[2][0] += a.z * bv.x; c[2][1] += a.z * bv.y; c[2][2] += a.z * bv.z; c[2][3] += a.z * bv.w;
                c[3][0] += a.w * bv.x; c[3][1] += a.w * bv.y; c[3][2] += a.w * bv.z; c[3][3] += a.w * bv.w;
            }
        }
        const float4 bv = *(const float4*)&l0b[j0 + (tx << 2)];
        const int col0 = j0 + (tx << 2);
#pragma unroll
        for (int i = 0; i < 4; ++i) {
            const int row = m0 + (ty << 2) + i;
            float4 o;
            o.x = fmaxf(c[i][0] + bv.x, 0.f); o.y = fmaxf(c[i][1] + bv.y, 0.f);
            o.z = fmaxf(c[i][2] + bv.z, 0.f); o.w = fmaxf(c[i][3] + bv.w, 0.f);
            *(float4*)&xh[(size_t)row * 128 + col0] = o;
            _Float16* base = Ax + (size_t)row * 128 + col0;
            base[0] = (_Float16)o.x; base[1] = (_Float16)o.y;
            base[2] = (_Float16)o.z; base[3] = (_Float16)o.w;
        }
    }
}

// ---------------------------------------------------------------------------
// FUSED: block 0 = exclusive prefix sum of odeg (the 1-CU scan bubble now
// hides under convb's 6528 blocks, which don't depend on it).
// blocks 1.. = Big B'T[t][j(4352)][128] fp16 build.
// ---------------------------------------------------------------------------
__global__ __launch_bounds__(256) void scan_convb_k(
    const int* __restrict__ odeg, int* __restrict__ ocur,
    const float* __restrict__ w2, const float* __restrict__ b2,
    const float* __restrict__ rw, _Float16* __restrict__ BT)
{
    __shared__ int ps[256];
    const int t = threadIdx.x;
    if (blockIdx.x == 0) {
        const int base = t * 16;
        int l[16]; int s = 0;
#pragma unroll
        for (int i = 0; i < 16; ++i) { l[i] = s; s += odeg[base + i]; }
        ps[t] = s;
        __syncthreads();
        for (int d = 1; d < 256; d <<= 1) {
            int v = (t >= d) ? ps[t - d] : 0;
            __syncthreads();
            ps[t] += v;
            __syncthreads();
        }
        const int excl = (t == 0) ? 0 : ps[t - 1];
#pragma unroll
        for (int i = 0; i < 16; ++i) ocur[base + i] = excl + l[i];
    } else {
        const int bb = blockIdx.x - 1;
        const int tt = bb / 2176;
        const int idx = (bb % 2176) * 256 + t;        // 4352*128
        const int j = idx >> 7, h = idx & 127;
        float v;
        if (j < 4096)      v = w2[(size_t)tt * 524288 + (size_t)(j >> 7) * 16384 + h * 128 + (j & 127)];
        else if (j < 4224) v = b2[tt * 16384 + h * 128 + (j - 4096)];
        else               v = rw[tt * 16384 + h * 128 + (j - 4224)];
        BT[(size_t)tt * 557056 + (size_t)j * 128 + h] = (_Float16)v;
    }
}

// counting-sort scatter by source + per-edge coefficient tables + alive-mask
__global__ void scatter_k(const int* __restrict__ ei, const float* __restrict__ eattr,
                          const float* __restrict__ w1, const float* __restrict__ b1,
                          const float* __restrict__ deg, int* __restrict__ ocur,
                          int2* __restrict__ rc, float* __restrict__ ehP,
                          int* __restrict__ kflag) {
    __shared__ unsigned bm[3];
    if (threadIdx.x < 3) bm[threadIdx.x] = 0u;
    __syncthreads();
    const int e = blockIdx.x * 256 + threadIdx.x;
    const int r = ei[e], c = ei[EE + e];
    const int pos = atomicAdd(&ocur[r], 1);
    rc[pos] = make_int2(r, c);
    const float d = deg[c];
    const float inv = d > 0.f ? 1.0f / d : 0.0f;
    const float ea = eattr[e];
    for (int t = 0; t < 3; ++t) {
        float* dst = ehP + ((size_t)t * EE + pos) * 33;
        unsigned m = 0;
        for (int k = 0; k < 32; ++k) {
            float v = ea * w1[t * 32 + k] + b1[t * 32 + k];
            float w = (v > 0.f ? v : 0.f) * inv;
            dst[k] = w;
            if (w != 0.f) m |= 1u << k;
        }
        dst[32] = inv;
        if (m) atomicOr(&bm[t], m);
    }
    __syncthreads();
    if (threadIdx.x < 3 && bm[threadIdx.x])
        atomicOr((unsigned*)&kflag[threadIdx.x], bm[threadIdx.x]);
}

// ---------------------------------------------------------------------------
// Edge gather + scatter over ALIVE channels only (compacted bigC slots)
// ---------------------------------------------------------------------------
__global__ __launch_bounds__(256) void edge_msg_k(
    const int2* __restrict__ rc, const float* __restrict__ ehP,
    const _Float16* __restrict__ U, float* __restrict__ agg,
    const int* __restrict__ kflag)
{
    __shared__ float eh[2][33];
    __shared__ unsigned char kls[32];
    const int b = blockIdx.x;                      // 4096 pairs
    const int p0 = ((b & 7) * 512 + (b >> 3)) * 2; // XCD-contiguous sorted ranges
    const int half = threadIdx.x >> 7;
    const int o = threadIdx.x & 127;
    const unsigned f = *(const unsigned*)kflag;
    if (threadIdx.x < 32 && ((f >> threadIdx.x) & 1u))
        kls[__popc(f & ((1u << threadIdx.x) - 1u))] = (unsigned char)threadIdx.x;
    if (o < 33) eh[half][o] = ehP[(size_t)(p0 + half) * 33 + o];
    __syncthreads();
    const int nk = __popc(f);
    const int2 e = rc[p0 + half];
    const _Float16* Ur = U + (size_t)e.x * ULD;
    float acc = eh[half][32] * (float)Ur[4096 + o];
#pragma unroll 4
    for (int i = 0; i < nk; ++i)
        acc += eh[half][kls[i]] * (float)Ur[i * 128 + o];
    atomicAdd(&agg[(size_t)e.y * 128 + o], acc);
}

__global__ __launch_bounds__(128) void final_k(
    const float* __restrict__ pooled, const float* __restrict__ cnt,
    const float* __restrict__ l1w, const float* __restrict__ l1b,
    const float* __restrict__ l2w, const float* __restrict__ l2b,
    float* __restrict__ out)
{
    __shared__ float gv[128];
    __shared__ float sy[64];
    const int t = threadIdx.x;
    for (int g = 0; g < GG; ++g) {
        float c = cnt[g]; c = c > 1.f ? c : 1.f;
        gv[t] = pooled[g * 128 + t] / c;
        __syncthreads();
        if (t < 64) {
            float y = l1b[t];
            for (int h = 0; h < 128; ++h) y += gv[h] * l1w[h * 64 + t];
            y = y > 0.f ? y : 0.f;
            sy[t] = y * l2w[t];
        }
        __syncthreads();
        if (t == 0) {
            float s = l2b[0];
            for (int j = 0; j < 64; ++j) s += sy[j];
            out[g] = s;
        }
        __syncthreads();
    }
}

extern "C" void kernel_launch(void* const* d_in, const int* in_sizes, int n_in,
                              void* d_out, int out_size, void* d_ws, size_t ws_size,
                              hipStream_t stream) {
    const float* x      = (const float*)d_in[0];
    const int*   ei     = (const int*)d_in[1];
    const float* eattr  = (const float*)d_in[2];
    const int*   batch  = (const int*)d_in[3];
    const float* lin0_w = (const float*)d_in[4];
    const float* lin0_b = (const float*)d_in[5];
    const float* nn_w1  = (const float*)d_in[6];
    const float* nn_b1  = (const float*)d_in[7];
    const float* nn_w2  = (const float*)d_in[8];
    const float* nn_b2  = (const float*)d_in[9];
    const float* root_w = (const float*)d_in[10];
    const float* conv_b = (const float*)d_in[11];
    const float* gwih   = (const float*)d_in[12];
    const float* gwhh   = (const float*)d_in[13];
    const float* gbih   = (const float*)d_in[14];
    const float* gbhh   = (const float*)d_in[15];
    const float* l1w    = (const float*)d_in[16];
    const float* l1b    = (const float*)d_in[17];
    const float* l2w    = (const float*)d_in[18];
    const float* l2b    = (const float*)d_in[19];
    float* out = (float*)d_out;
    float* ws  = (float*)d_ws;

    // ---- workspace layout (float offsets; zero region first, contiguous) ----
    float*    agg0   = ws;                          // 3 x [4096,128]
    float*    pooled = ws + 1572864;                // [8,128]
    float*    cnt    = ws + 1573888;                // [8]
    float*    deg    = ws + 1573896;                // [4096]
    int*      odeg   = (int*)(ws + 1577992);        // [4096]
    int*      kflag  = (int*)(ws + 1582088);        // [3] alive masks (+pad)
    // zero region ends at 1582096 floats = 6328384 bytes
    int*      ocur   = (int*)(ws + 1582096);        // [4096]
    int2*     rc     = (int2*)(ws + 1586192);       // [8192]
    float*    ehP    = ws + 1602576;                // [3,8192,33]
    float*    xhA    = ws + 2413584;                // [4096,128] fp32
    float*    xhB    = ws + 2937872;                // [4096,128] fp32 (was g1)
    _Float16* AxB    = (_Float16*)(ws + 4510736);   // [4096,128] fp16 (was g2)
    _Float16* bigC   = (_Float16*)(ws + 6083600);   // [4096,4352] fp16
    _Float16* AxA    = (_Float16*)(ws + 14996496);  // [4096,128] fp16
    _Float16* BTu    = (_Float16*)(ws + 15258640);  // 3 x [4352,128] fp16
    _Float16* Bih16  = (_Float16*)(ws + 16094224);  // [384,128] fp16
    _Float16* Bhh16  = (_Float16*)(ws + 16118800);  // [384,128] fp16

    hipMemsetAsync(agg0, 0, 6328384, stream);
    setup_lin0_k<<<368, 256, 0, stream>>>(gwih, gwhh, Bih16, Bhh16, ei, batch,
                                          deg, odeg, cnt, x, lin0_w, lin0_b,
                                          xhA, AxA);
    scan_convb_k<<<6529, 256, 0, stream>>>(odeg, ocur, nn_w2, nn_b2, root_w, BTu);
    scatter_k<<<EE / 256, 256, 0, stream>>>(ei, eattr, nn_w1, nn_b1, deg, ocur, rc, ehP, kflag);

    float*    xh_in = xhA;  float*    xh_out = xhB;
    _Float16* Ax_in = AxA;  _Float16* Ax_out = AxB;
    for (int t = 0; t < 3; ++t) {
        float* agg = agg0 + (size_t)t * 524288;
        mgemm16_k<<<dim3(34, 32), 256, 0, stream>>>(Ax_in, BTu + (size_t)t * 557056, bigC, kflag + t);
        edge_msg_k<<<EE / 2, 256, 0, stream>>>(rc, ehP + (size_t)t * EE * 33, bigC, agg, kflag + t);
        gru_gate_k<<<dim3(4, 64), 256, 0, stream>>>(bigC, agg, conv_b + t * 128,
                                                    Ax_in, xh_in, Bih16, Bhh16,
                                                    gbih, gbhh, xh_out, Ax_out,
                                                    batch, (t == 2) ? pooled : nullptr);
        float* tf = xh_in; xh_in = xh_out; xh_out = tf;
        _Float16* th = Ax_in; Ax_in = Ax_out; Ax_out = th;
    }

    final_k<<<1, 128, 0, stream>>>(pooled, cnt, l1w, l1b, l2w, l2b, out);
}

// Round 3
// 264.977 us; speedup vs baseline: 1.1129x; 1.1129x over previous
//
#include <hip/hip_runtime.h>
#include <math.h>

#define NN 4096
#define EE 8192
#define HH 128
#define GG 8
#define ULD 4352          // big GEMM cols: 4096 (W2) + 128 (b2) + 128 (root)

typedef __attribute__((ext_vector_type(8))) _Float16 half8;
typedef __attribute__((ext_vector_type(4))) float floatx4;

__device__ __forceinline__ void ldst16(const _Float16* g, void* l) {
    __builtin_amdgcn_global_load_lds(
        (const __attribute__((address_space(1))) unsigned int*)g,
        (__attribute__((address_space(3))) unsigned int*)l, 16, 0, 0);
}

// ---------------------------------------------------------------------------
// fp16 MFMA GEMM: C[M,*] = A[M,128] @ BT[N,128]^T, C stored fp16.
// 128x128 tile/block, 4 waves (2x2 of 64x64), BK=32, K=128 (4 iters).
// Dead-channel pruning: blockIdx.x < 32 indexes a W2 k-slice; if kflag bit
// clear the slice is never read -> exit. Alive slices write COMPACTED cols.
// ---------------------------------------------------------------------------
__global__ __launch_bounds__(256) void mgemm16_k(
    const _Float16* __restrict__ A, const _Float16* __restrict__ B,
    _Float16* __restrict__ C, const int* __restrict__ kflag)
{
    const int kk = blockIdx.x;
    int cbase;
    if (kk < 32) {
        const unsigned f = *(const unsigned*)kflag;
        if (!((f >> kk) & 1u)) return;               // dead slice: no reader
        cbase = __popc(f & ((1u << kk) - 1u)) << 7;  // compacted col slot
    } else {
        cbase = kk << 7;                             // b2 / root fixed slots
    }

    __shared__ __align__(16) _Float16 As[128 * 32];  // [row][k]
    __shared__ __align__(16) _Float16 Bs[128 * 32];  // [col][k]
    const int tid = threadIdx.x;
    const int lane = tid & 63, wave = tid >> 6;
    const int m0 = blockIdx.y * 128, n0 = kk * 128;  // n0: weight-row base
    const int wr = (wave >> 1) * 64, wc = (wave & 1) * 64;
    const int fm = lane & 15, fq = lane >> 4;

    const int srow = tid >> 2, soff = (tid & 3) << 3;
    const _Float16* gA0 = A + (size_t)(m0 + srow) * 128 + soff;
    const _Float16* gA1 = gA0 + (size_t)64 * 128;
    const _Float16* gB0 = B + (size_t)(n0 + srow) * 128 + soff;
    const _Float16* gB1 = gB0 + (size_t)64 * 128;
    char* lA0 = (char*)As + tid * 16;  char* lA1 = (char*)As + (tid + 256) * 16;
    char* lB0 = (char*)Bs + tid * 16;  char* lB1 = (char*)Bs + (tid + 256) * 16;

    floatx4 acc[4][4] = {};
    for (int k0 = 0; k0 < 128; k0 += 32) {
        __syncthreads();
        ldst16(gA0 + k0, lA0); ldst16(gA1 + k0, lA1);
        ldst16(gB0 + k0, lB0); ldst16(gB1 + k0, lB1);
        __syncthreads();
        half8 af[4], bf[4];
#pragma unroll
        for (int i = 0; i < 4; ++i)
            af[i] = *(const half8*)&As[(wr + i * 16 + fm) * 32 + fq * 8];
#pragma unroll
        for (int j = 0; j < 4; ++j)
            bf[j] = *(const half8*)&Bs[(wc + j * 16 + fm) * 32 + fq * 8];
#pragma unroll
        for (int i = 0; i < 4; ++i)
#pragma unroll
            for (int j = 0; j < 4; ++j)
                acc[i][j] = __builtin_amdgcn_mfma_f32_16x16x32_f16(
                    af[i], bf[j], acc[i][j], 0, 0, 0);
    }
    // C/D layout: col = lane&15, row = (lane>>4)*4 + reg  [m89; dtype-indep]
    const int er = fq * 4, ec = fm;
#pragma unroll
    for (int i = 0; i < 4; ++i) {
        const int gr = m0 + wr + i * 16 + er;
#pragma unroll
        for (int j = 0; j < 4; ++j) {
            const int gc = cbase + wc + j * 16 + ec;
#pragma unroll
            for (int r = 0; r < 4; ++r)
                C[(size_t)(gr + r) * ULD + gc] = (_Float16)acc[i][j][r];
        }
    }
}

// ---------------------------------------------------------------------------
// GRU GEMM (R1-verified structure), both gates in one dispatch via
// blockIdx.z, with mcomb fused into the z=0 A-staging:
// A(z=0) = m = relu(bigC_root + agg + conv_b) fp16; A(z=1) = Ax.
// B rows = weight rows (K=128). C fp32 [4096,384].
// LDS padded to 40 halves/row (80B stride -> conflict-free ds_read_b128).
// ---------------------------------------------------------------------------
__global__ __launch_bounds__(256) void gru_k(
    const _Float16* __restrict__ bigC, const float* __restrict__ agg,
    const float* __restrict__ cb, const _Float16* __restrict__ Ax,
    const _Float16* __restrict__ Bih, const _Float16* __restrict__ Bhh,
    const float* __restrict__ bih, const float* __restrict__ bhh,
    float* __restrict__ g1, float* __restrict__ g2)
{
    const int z = blockIdx.z;
    const _Float16* B = z ? Bhh : Bih;
    const float* bias = z ? bhh : bih;
    float* C = z ? g2 : g1;

    __shared__ __align__(16) _Float16 As[128 * 40];
    __shared__ __align__(16) _Float16 Bs[128 * 40];
    const int tid = threadIdx.x;
    const int lane = tid & 63, wave = tid >> 6;
    const int m0 = blockIdx.y * 128, n0 = blockIdx.x * 128;
    const int wr = (wave >> 1) * 64, wc = (wave & 1) * 64;
    const int fm = lane & 15, fq = lane >> 4;

    floatx4 acc[4][4] = {};
    for (int k0 = 0; k0 < 128; k0 += 32) {
        __syncthreads();
#pragma unroll
        for (int c = tid; c < 512; c += 256) {
            const int row = c >> 2, seg = (c & 3) << 3;
            // stage A
            if (z == 0) {
                const int mr = m0 + row;
                const half8 cv = *(const half8*)&bigC[(size_t)mr * ULD + 4224 + k0 + seg];
                const float4 a0 = *(const float4*)&agg[(size_t)mr * 128 + k0 + seg];
                const float4 a1 = *(const float4*)&agg[(size_t)mr * 128 + k0 + seg + 4];
                const float4 c0 = *(const float4*)&cb[k0 + seg];
                const float4 c1 = *(const float4*)&cb[k0 + seg + 4];
                _Float16 v8[8];
                float v;
                v = (float)cv[0] + a0.x + c0.x; v8[0] = (_Float16)(v > 0.f ? v : 0.f);
                v = (float)cv[1] + a0.y + c0.y; v8[1] = (_Float16)(v > 0.f ? v : 0.f);
                v = (float)cv[2] + a0.z + c0.z; v8[2] = (_Float16)(v > 0.f ? v : 0.f);
                v = (float)cv[3] + a0.w + c0.w; v8[3] = (_Float16)(v > 0.f ? v : 0.f);
                v = (float)cv[4] + a1.x + c1.x; v8[4] = (_Float16)(v > 0.f ? v : 0.f);
                v = (float)cv[5] + a1.y + c1.y; v8[5] = (_Float16)(v > 0.f ? v : 0.f);
                v = (float)cv[6] + a1.z + c1.z; v8[6] = (_Float16)(v > 0.f ? v : 0.f);
                v = (float)cv[7] + a1.w + c1.w; v8[7] = (_Float16)(v > 0.f ? v : 0.f);
                *(half8*)&As[row * 40 + seg] = *(half8*)v8;
            } else {
                *(half8*)&As[row * 40 + seg] =
                    *(const half8*)&Ax[(size_t)(m0 + row) * 128 + k0 + seg];
            }
            // stage B
            *(half8*)&Bs[row * 40 + seg] =
                *(const half8*)&B[(size_t)(n0 + row) * 128 + k0 + seg];
        }
        __syncthreads();
        half8 af[4], bf[4];
#pragma unroll
        for (int i = 0; i < 4; ++i)
            af[i] = *(const half8*)&As[(wr + i * 16 + fm) * 40 + fq * 8];
#pragma unroll
        for (int j = 0; j < 4; ++j)
            bf[j] = *(const half8*)&Bs[(wc + j * 16 + fm) * 40 + fq * 8];
#pragma unroll
        for (int i = 0; i < 4; ++i)
#pragma unroll
            for (int j = 0; j < 4; ++j)
                acc[i][j] = __builtin_amdgcn_mfma_f32_16x16x32_f16(
                    af[i], bf[j], acc[i][j], 0, 0, 0);
    }
    const int er = fq * 4, ec = fm;
#pragma unroll
    for (int i = 0; i < 4; ++i) {
        const int gr = m0 + wr + i * 16 + er;
#pragma unroll
        for (int j = 0; j < 4; ++j) {
            const int gc = n0 + wc + j * 16 + ec;
            const float bv = bias[gc];
#pragma unroll
            for (int r = 0; r < 4; ++r)
                C[(size_t)(gr + r) * 384 + gc] = acc[i][j][r] + bv;
        }
    }
}

// GRU gate combine; updates xh fp32 + Ax fp16; fused pooling on last step
__global__ void gate_k(const float* __restrict__ G1, const float* __restrict__ G2,
                       float* __restrict__ xh, _Float16* __restrict__ Ax,
                       const int* __restrict__ batch, float* __restrict__ pooled) {
    const int idx = blockIdx.x * 256 + threadIdx.x;
    const int n = idx >> 7, o = idx & 127;
    const size_t b = (size_t)n * 384;
    float ir = G1[b + o], iz = G1[b + 128 + o], in_ = G1[b + 256 + o];
    float hr = G2[b + o], hz = G2[b + 128 + o], hn = G2[b + 256 + o];
    float r = 1.f / (1.f + expf(-(ir + hr)));
    float z = 1.f / (1.f + expf(-(iz + hz)));
    float nv = tanhf(in_ + r * hn);
    float hv = (1.f - z) * nv + z * xh[idx];
    xh[idx] = hv;
    Ax[idx] = (_Float16)hv;
    if (pooled) atomicAdd(&pooled[batch[n] * 128 + o], hv);
}

// ---------------------------------------------------------------------------
// FUSED setup: b<192 GRU weight cast; b<224 degree hists; b<240 graph count;
// b>=240 lin0 GEMM (xh = relu(x @ w + b), also writes Ax fp16).
// ---------------------------------------------------------------------------
__global__ __launch_bounds__(256) void setup_lin0_k(
    const float* __restrict__ wih, const float* __restrict__ whh,
    _Float16* __restrict__ Bih, _Float16* __restrict__ Bhh,
    const int* __restrict__ ei, const int* __restrict__ batch,
    float* __restrict__ deg, int* __restrict__ odeg, float* __restrict__ cnt,
    const float* __restrict__ x, const float* __restrict__ l0w,
    const float* __restrict__ l0b, float* __restrict__ xh,
    _Float16* __restrict__ Ax)
{
    __shared__ float loc8[GG];
    __shared__ float As[16][64];
    __shared__ float Bs[16][64];
    const int b = blockIdx.x, t = threadIdx.x;
    if (b < 192) {
        const int idx = b * 256 + t;           // 384*128
        Bih[idx] = (_Float16)wih[idx];
        Bhh[idx] = (_Float16)whh[idx];
    } else if (b < 224) {
        const int e = (b - 192) * 256 + t;     // 8192
        atomicAdd(&deg[ei[EE + e]], 1.0f);
        atomicAdd(&odeg[ei[e]], 1);
    } else if (b < 240) {
        const int n = (b - 224) * 256 + t;     // 4096
        if (t < GG) loc8[t] = 0.f;
        __syncthreads();
        atomicAdd(&loc8[batch[n]], 1.0f);
        __syncthreads();
        if (t < GG) atomicAdd(&cnt[t], loc8[t]);
    } else {
        // lin0: 128 blocks, 64x64 tile
        const int bb = b - 240;
        const int j0 = (bb & 1) * 64;
        const int m0 = (bb >> 1) * 64;
        const int tx = t & 15, ty = t >> 4;
        const int arow = t >> 2, acol = (t & 3) << 2;
        const int bk = t >> 4, bj = (t & 15) << 2;
        float c[4][4] = {};
        for (int k0 = 0; k0 < 64; k0 += 16) {
            __syncthreads();
            float4 av = *(const float4*)&x[(size_t)(m0 + arow) * 64 + k0 + acol];
            As[acol + 0][arow] = av.x;
            As[acol + 1][arow] = av.y;
            As[acol + 2][arow] = av.z;
            As[acol + 3][arow] = av.w;
            *(float4*)&Bs[bk][bj] = *(const float4*)&l0w[(size_t)(k0 + bk) * 128 + j0 + bj];
            __syncthreads();
#pragma unroll
            for (int kk = 0; kk < 16; ++kk) {
                const float4 a = *(const float4*)&As[kk][ty << 2];
                const float4 bv = *(const float4*)&Bs[kk][tx << 2];
                c[0][0] += a.x * bv.x; c[0][1] += a.x * bv.y; c[0][2] += a.x * bv.z; c[0][3] += a.x * bv.w;
                c[1][0] += a.y * bv.x; c[1][1] += a.y * bv.y; c[1][2] += a.y * bv.z; c[1][3] += a.y * bv.w;
                c[2][0] += a.z * bv.x; c[2][1] += a.z * bv.y; c[2][2] += a.z * bv.z; c[2][3] += a.z * bv.w;
                c[3][0] += a.w * bv.x; c[3][1] += a.w * bv.y; c[3][2] += a.w * bv.z; c[3][3] += a.w * bv.w;
            }
        }
        const float4 bv = *(const float4*)&l0b[j0 + (tx << 2)];
        const int col0 = j0 + (tx << 2);
#pragma unroll
        for (int i = 0; i < 4; ++i) {
            const int row = m0 + (ty << 2) + i;
            float4 o;
            o.x = fmaxf(c[i][0] + bv.x, 0.f); o.y = fmaxf(c[i][1] + bv.y, 0.f);
            o.z = fmaxf(c[i][2] + bv.z, 0.f); o.w = fmaxf(c[i][3] + bv.w, 0.f);
            *(float4*)&xh[(size_t)row * 128 + col0] = o;
            _Float16* base = Ax + (size_t)row * 128 + col0;
            base[0] = (_Float16)o.x; base[1] = (_Float16)o.y;
            base[2] = (_Float16)o.z; base[3] = (_Float16)o.w;
        }
    }
}

// ---------------------------------------------------------------------------
// FUSED: block 0 = exclusive prefix sum of odeg (1-CU scan hides under the
// 6528 convb blocks, which don't depend on it). blocks 1.. = BT build.
// ---------------------------------------------------------------------------
__global__ __launch_bounds__(256) void scan_convb_k(
    const int* __restrict__ odeg, int* __restrict__ ocur,
    const float* __restrict__ w2, const float* __restrict__ b2,
    const float* __restrict__ rw, _Float16* __restrict__ BT)
{
    __shared__ int ps[256];
    const int t = threadIdx.x;
    if (blockIdx.x == 0) {
        const int base = t * 16;
        int l[16]; int s = 0;
#pragma unroll
        for (int i = 0; i < 16; ++i) { l[i] = s; s += odeg[base + i]; }
        ps[t] = s;
        __syncthreads();
        for (int d = 1; d < 256; d <<= 1) {
            int v = (t >= d) ? ps[t - d] : 0;
            __syncthreads();
            ps[t] += v;
            __syncthreads();
        }
        const int excl = (t == 0) ? 0 : ps[t - 1];
#pragma unroll
        for (int i = 0; i < 16; ++i) ocur[base + i] = excl + l[i];
    } else {
        const int bb = blockIdx.x - 1;
        const int tt = bb / 2176;
        const int idx = (bb % 2176) * 256 + t;        // 4352*128
        const int j = idx >> 7, h = idx & 127;
        float v;
        if (j < 4096)      v = w2[(size_t)tt * 524288 + (size_t)(j >> 7) * 16384 + h * 128 + (j & 127)];
        else if (j < 4224) v = b2[tt * 16384 + h * 128 + (j - 4096)];
        else               v = rw[tt * 16384 + h * 128 + (j - 4224)];
        BT[(size_t)tt * 557056 + (size_t)j * 128 + h] = (_Float16)v;
    }
}

// ---------------------------------------------------------------------------
// Counting-sort scatter, WAVE-PER-EDGE (was thread-per-edge with 99 serial
// scattered stores): lanes 0..32 write the coefficient row in parallel;
// alive-mask via __ballot. 2048 blocks x 4 waves = 8192 edges.
// ---------------------------------------------------------------------------
__global__ __launch_bounds__(256) void scatter_k(
    const int* __restrict__ ei, const float* __restrict__ eattr,
    const float* __restrict__ w1, const float* __restrict__ b1,
    const float* __restrict__ deg, int* __restrict__ ocur,
    int2* __restrict__ rc, float* __restrict__ ehP, int* __restrict__ kflag)
{
    __shared__ unsigned bm[3];
    if (threadIdx.x < 3) bm[threadIdx.x] = 0u;
    __syncthreads();
    const int wave = threadIdx.x >> 6, lane = threadIdx.x & 63;
    const int e = blockIdx.x * 4 + wave;
    const int r = ei[e], c = ei[EE + e];
    int pos = 0;
    if (lane == 0) pos = atomicAdd(&ocur[r], 1);
    pos = __shfl(pos, 0);
    if (lane == 0) rc[pos] = make_int2(r, c);
    const float d = deg[c];
    const float inv = d > 0.f ? 1.0f / d : 0.0f;
    const float ea = eattr[e];
#pragma unroll
    for (int t = 0; t < 3; ++t) {
        float w = inv;                        // lane 32: inv_deg slot
        if (lane < 32) {
            float v = ea * w1[t * 32 + lane] + b1[t * 32 + lane];
            w = (v > 0.f ? v : 0.f) * inv;
        }
        const unsigned long long mb = __ballot(lane < 32 && w != 0.f);
        if (lane < 33) ehP[((size_t)t * EE + pos) * 33 + lane] = w;
        if (lane == 0 && (unsigned)mb) atomicOr(&bm[t], (unsigned)mb);
    }
    __syncthreads();
    if (threadIdx.x < 3 && bm[threadIdx.x])
        atomicOr((unsigned*)&kflag[threadIdx.x], bm[threadIdx.x]);
}

// ---------------------------------------------------------------------------
// Edge gather + scatter over ALIVE channels only (compacted bigC slots)
// ---------------------------------------------------------------------------
__global__ __launch_bounds__(256) void edge_msg_k(
    const int2* __restrict__ rc, const float* __restrict__ ehP,
    const _Float16* __restrict__ U, float* __restrict__ agg,
    const int* __restrict__ kflag)
{
    __shared__ float eh[2][33];
    __shared__ unsigned char kls[32];
    const int b = blockIdx.x;                      // 4096 pairs
    const int p0 = ((b & 7) * 512 + (b >> 3)) * 2; // XCD-contiguous sorted ranges
    const int half = threadIdx.x >> 7;
    const int o = threadIdx.x & 127;
    const unsigned f = *(const unsigned*)kflag;
    if (threadIdx.x < 32 && ((f >> threadIdx.x) & 1u))
        kls[__popc(f & ((1u << threadIdx.x) - 1u))] = (unsigned char)threadIdx.x;
    if (o < 33) eh[half][o] = ehP[(size_t)(p0 + half) * 33 + o];
    __syncthreads();
    const int nk = __popc(f);
    const int2 e = rc[p0 + half];
    const _Float16* Ur = U + (size_t)e.x * ULD;
    float acc = eh[half][32] * (float)Ur[4096 + o];
#pragma unroll 4
    for (int i = 0; i < nk; ++i)
        acc += eh[half][kls[i]] * (float)Ur[i * 128 + o];
    atomicAdd(&agg[(size_t)e.y * 128 + o], acc);
}

// ---------------------------------------------------------------------------
// Readout, one block per graph (was 1 block serial over 8 graphs);
// wave-shuffle reduction for the final dot product.
// ---------------------------------------------------------------------------
__global__ __launch_bounds__(128) void final_k(
    const float* __restrict__ pooled, const float* __restrict__ cnt,
    const float* __restrict__ l1w, const float* __restrict__ l1b,
    const float* __restrict__ l2w, const float* __restrict__ l2b,
    float* __restrict__ out)
{
    __shared__ float gv[128];
    const int g = blockIdx.x, t = threadIdx.x;
    float c = cnt[g]; c = c > 1.f ? c : 1.f;
    gv[t] = pooled[g * 128 + t] / c;
    __syncthreads();
    if (t < 64) {
        float y = l1b[t];
        for (int h = 0; h < 128; ++h) y += gv[h] * l1w[h * 64 + t];
        y = y > 0.f ? y : 0.f;
        float s = y * l2w[t];
#pragma unroll
        for (int off = 32; off > 0; off >>= 1)
            s += __shfl_down(s, off);
        if (t == 0) out[g] = s + l2b[0];
    }
}

extern "C" void kernel_launch(void* const* d_in, const int* in_sizes, int n_in,
                              void* d_out, int out_size, void* d_ws, size_t ws_size,
                              hipStream_t stream) {
    const float* x      = (const float*)d_in[0];
    const int*   ei     = (const int*)d_in[1];
    const float* eattr  = (const float*)d_in[2];
    const int*   batch  = (const int*)d_in[3];
    const float* lin0_w = (const float*)d_in[4];
    const float* lin0_b = (const float*)d_in[5];
    const float* nn_w1  = (const float*)d_in[6];
    const float* nn_b1  = (const float*)d_in[7];
    const float* nn_w2  = (const float*)d_in[8];
    const float* nn_b2  = (const float*)d_in[9];
    const float* root_w = (const float*)d_in[10];
    const float* conv_b = (const float*)d_in[11];
    const float* gwih   = (const float*)d_in[12];
    const float* gwhh   = (const float*)d_in[13];
    const float* gbih   = (const float*)d_in[14];
    const float* gbhh   = (const float*)d_in[15];
    const float* l1w    = (const float*)d_in[16];
    const float* l1b    = (const float*)d_in[17];
    const float* l2w    = (const float*)d_in[18];
    const float* l2b    = (const float*)d_in[19];
    float* out = (float*)d_out;
    float* ws  = (float*)d_ws;

    // ---- workspace layout (float offsets; zero region first, contiguous) ----
    float*    agg0   = ws;                          // 3 x [4096,128]
    float*    pooled = ws + 1572864;                // [8,128]
    float*    cnt    = ws + 1573888;                // [8]
    float*    deg    = ws + 1573896;                // [4096]
    int*      odeg   = (int*)(ws + 1577992);        // [4096]
    int*      kflag  = (int*)(ws + 1582088);        // [3] alive masks (+pad)
    // zero region ends at 1582096 floats = 6328384 bytes
    int*      ocur   = (int*)(ws + 1582096);        // [4096]
    int2*     rc     = (int2*)(ws + 1586192);       // [8192]
    float*    ehP    = ws + 1602576;                // [3,8192,33]
    float*    xh     = ws + 2413584;                // [4096,128]
    float*    g1     = ws + 2937872;                // [4096,384]
    float*    g2     = ws + 4510736;                // [4096,384]
    _Float16* bigC   = (_Float16*)(ws + 6083600);   // [4096,4352] fp16
    _Float16* Ax     = (_Float16*)(ws + 14996496);  // [4096,128] fp16
    _Float16* BTu    = (_Float16*)(ws + 15258640);  // 3 x [4352,128] fp16
    _Float16* Bih16  = (_Float16*)(ws + 16094224);  // [384,128] fp16
    _Float16* Bhh16  = (_Float16*)(ws + 16118800);  // [384,128] fp16

    hipMemsetAsync(agg0, 0, 6328384, stream);
    setup_lin0_k<<<368, 256, 0, stream>>>(gwih, gwhh, Bih16, Bhh16, ei, batch,
                                          deg, odeg, cnt, x, lin0_w, lin0_b,
                                          xh, Ax);
    scan_convb_k<<<6529, 256, 0, stream>>>(odeg, ocur, nn_w2, nn_b2, root_w, BTu);
    scatter_k<<<2048, 256, 0, stream>>>(ei, eattr, nn_w1, nn_b1, deg, ocur, rc, ehP, kflag);

    for (int t = 0; t < 3; ++t) {
        float* agg = agg0 + (size_t)t * 524288;
        mgemm16_k<<<dim3(34, 32), 256, 0, stream>>>(Ax, BTu + (size_t)t * 557056, bigC, kflag + t);
        edge_msg_k<<<EE / 2, 256, 0, stream>>>(rc, ehP + (size_t)t * EE * 33, bigC, agg, kflag + t);
        gru_k<<<dim3(3, 32, 2), 256, 0, stream>>>(bigC, agg, conv_b + t * 128, Ax,
                                                  Bih16, Bhh16, gbih, gbhh, g1, g2);
        gate_k<<<2048, 256, 0, stream>>>(g1, g2, xh, Ax, batch,
                                         (t == 2) ? pooled : nullptr);
    }

    final_k<<<GG, 128, 0, stream>>>(pooled, cnt, l1w, l1b, l2w, l2b, out);
}